// Round 3
// baseline (812.118 us; speedup 1.0000x reference)
//
#include <hip/hip_runtime.h>
#include <hip/hip_cooperative_groups.h>
#include <math.h>

namespace cg = cooperative_groups;

// Problem constants (fixed by setup_inputs)
#define B   8
#define C   512
#define H   128
#define W   128
#define HW  16384          // H*W
#define HWQ 4096           // HW/4 (float4 quads per image plane)
#define BHW 131072         // B*HW
#define NCHUNK 8           // channel chunks
#define CPC    64          // channels per chunk

// native clang vector for nontemporal builtins (HIP_vector_type is rejected)
typedef float nfloat4 __attribute__((ext_vector_type(4)));

// ---------------------------------------------------------------------------
// One cooperative kernel, 1024 blocks x 256 threads (4 blocks/CU, co-resident).
// P1: conv partials (channel-split 8x64, one float4 quad/thread)
// P2: reduce partials -> xproj          (first 128 blocks)
// P3: per-(b,mask) softmax stats -> coef (first 128 blocks)
// P4: scale recomputed on the fly + apply, descending 4MiB bands for L3 reuse,
//     nontemporal output stores so the output never evicts the resident input.
// ---------------------------------------------------------------------------
__global__ __launch_bounds__(256, 4)
void fused_kernel(const float* __restrict__ in,
                  const float* __restrict__ wv,
                  float* __restrict__ partial,
                  float* __restrict__ xproj,
                  float* __restrict__ coef,
                  float* __restrict__ out) {
    cg::grid_group grid = cg::this_grid();
    __shared__ float sm[4];
    __shared__ float ss[4];

    const int tid = threadIdx.x;
    const int t   = blockIdx.x * 256 + tid;      // 0 .. 262143

    // ---------------- P1: conv partials ----------------
    {
        int chunk = t >> 15;                     // 0..7
        int quad  = t & 32767;                   // spatial quad over B*HW/4
        int b = quad >> 12;
        int q = quad & (HWQ - 1);

        const float4* inp = (const float4*)in
            + (size_t)b * (C * HWQ)
            + (size_t)chunk * CPC * HWQ
            + q;
        const float* wc = wv + chunk * CPC;

        float4 acc = make_float4(0.f, 0.f, 0.f, 0.f);
#pragma unroll 8
        for (int c = 0; c < CPC; ++c) {
            float4 v = inp[(size_t)c * HWQ];
            float wcc = wc[c];
            acc.x += v.x * wcc;
            acc.y += v.y * wcc;
            acc.z += v.z * wcc;
            acc.w += v.w * wcc;
        }
        ((float4*)partial)[(size_t)chunk * 32768 + quad] = acc;
    }
    grid.sync();

    // ---------------- P2: reduce -> xproj ----------------
    if (blockIdx.x < 128) {
        int u = blockIdx.x * 256 + tid;          // 0..32767 (quad over B*HW/4)
        float4 s = make_float4(0.f, 0.f, 0.f, 0.f);
#pragma unroll
        for (int ch = 0; ch < NCHUNK; ++ch) {
            float4 p = ((const float4*)partial)[(size_t)ch * 32768 + u];
            s.x += p.x;
            s.y += p.y;
            s.z += p.z;
            s.w += p.w;
        }
        ((float4*)xproj)[u] = s;
    }
    grid.sync();

    // ---------------- P3: softmax stats -> coef ----------------
    if (blockIdx.x < 128) {
        int bk = blockIdx.x;                     // 0..127
        int b = bk >> 4, k = bk & 15;
        int i = k >> 2, j = k & 3;
        int h0 = (16 * i + ((j >> 1) ? 64 : 0)) & (H - 1);
        int w0 = (16 * i + ((j & 1) ? 64 : 0)) & (W - 1);
        const float* x = xproj + b * HW;

        float v[16];
        float m = -1e30f;
#pragma unroll
        for (int it = 0; it < 16; ++it) {
            int p = tid + 256 * it;              // 0..4095 window pixel
            int r = p >> 6, c = p & 63;
            int h = (h0 + r) & (H - 1);
            int w = (w0 + c) & (W - 1);
            v[it] = x[h * W + w];
            m = fmaxf(m, v[it]);
        }
        for (int off = 32; off > 0; off >>= 1)
            m = fmaxf(m, __shfl_down(m, off, 64));
        int lane = tid & 63, wvi = tid >> 6;
        if (lane == 0) sm[wvi] = m;
        __syncthreads();
        m = fmaxf(fmaxf(sm[0], sm[1]), fmaxf(sm[2], sm[3]));

        float s = 0.f;
#pragma unroll
        for (int it = 0; it < 16; ++it)
            s += expf(v[it] - m);
        for (int off = 32; off > 0; off >>= 1)
            s += __shfl_down(s, off, 64);
        if (lane == 0) ss[wvi] = s;
        __syncthreads();
        if (tid == 0) {
            float Z = ss[0] + ss[1] + ss[2] + ss[3];
            coef[bk] = expf(-m) / Z;
        }
    }
    grid.sync();

    // ---------------- P4: scale-on-the-fly + apply ----------------
    {
        int q    = t & (HWQ - 1);                // spatial quad (fixed per thread)
        int cofs = t >> 12;                      // 0..63 channel offset
        int h  = q >> 5;                         // pixel row of the quad
        int w0 = (q & 31) * 4;                   // first pixel col of the quad

        for (int b = B - 1; b >= 0; --b) {       // descending batch (L3 recency)
            const float* cf = coef + b * 16;
            float4 xp = ((const float4*)xproj)[(b << 12) + q];

            // per-pixel mask-coef sum (same accumulation order as before)
            float a0 = 0.f, a1 = 0.f, a2 = 0.f, a3 = 0.f;
#pragma unroll
            for (int i = 0; i < 4; ++i) {
                int hr = (h - 16 * i) & (H - 1);
                int hterm = 4 * i + ((hr < 64) ? 0 : 2);
                int wr0 = (w0 + 0 - 16 * i) & (W - 1);
                int wr1 = (w0 + 1 - 16 * i) & (W - 1);
                int wr2 = (w0 + 2 - 16 * i) & (W - 1);
                int wr3 = (w0 + 3 - 16 * i) & (W - 1);
                a0 += cf[hterm + ((wr0 < 64) ? 0 : 1)];
                a1 += cf[hterm + ((wr1 < 64) ? 0 : 1)];
                a2 += cf[hterm + ((wr2 < 64) ? 0 : 1)];
                a3 += cf[hterm + ((wr3 < 64) ? 0 : 1)];
            }
            float4 s4;
            s4.x = 1.0f + expf(xp.x) * a0;
            s4.y = 1.0f + expf(xp.y) * a1;
            s4.z = 1.0f + expf(xp.z) * a2;
            s4.w = 1.0f + expf(xp.w) * a3;

            for (int band = 7; band >= 0; --band) {  // descending 4MiB bands
                int c = band * 64 + cofs;
                size_t g = ((size_t)(b * C + c) << 12) + q;   // float4 index
                float4 v = ((const float4*)in)[g];
                nfloat4 r;
                r.x = v.x * s4.x;
                r.y = v.y * s4.y;
                r.z = v.z * s4.z;
                r.w = v.w * s4.w;
                __builtin_nontemporal_store(r, (nfloat4*)((float4*)out + g));
            }
        }
    }
}

extern "C" void kernel_launch(void* const* d_in, const int* in_sizes, int n_in,
                              void* d_out, int out_size, void* d_ws, size_t ws_size,
                              hipStream_t stream) {
    const float* input  = (const float*)d_in[0];   // [8,512,128,128]
    const float* w_conv = (const float*)d_in[1];   // [512]
    float* out = (float*)d_out;                    // [8,512,128,128]

    // workspace layout (floats): partial[8*131072] | xproj[131072] | coef[128]
    float* ws      = (float*)d_ws;
    float* partial = ws;                               // 1,048,576 floats
    float* xproj   = ws + (size_t)NCHUNK * BHW;        // +131072
    float* coef    = xproj + BHW;                      // +128

    void* args[] = {
        (void*)&input, (void*)&w_conv, (void*)&partial,
        (void*)&xproj, (void*)&coef, (void*)&out
    };
    hipLaunchCooperativeKernel((const void*)fused_kernel,
                               dim3(1024), dim3(256), args, 0, stream);
}

// Round 5
// 483.538 us; speedup vs baseline: 1.6795x; 1.6795x over previous
//
#include <hip/hip_runtime.h>
#include <math.h>

// Problem constants (fixed by setup_inputs)
#define B   8
#define C   512
#define H   128
#define W   128
#define HW  16384          // H*W
#define HWQ 4096           // HW/4 (float4 quads per image plane)
#define BHW 131072         // B*HW
#define NCHUNK 32          // channel chunks (was 8) -> conv grid 4096 blocks
#define CPC    16          // channels per chunk

// native clang vector for nontemporal builtins (HIP_vector_type is rejected)
typedef float nfloat4 __attribute__((ext_vector_type(4)));

// ---------------------------------------------------------------------------
// Kernel 1: channel-dot partials. grid = NCHUNK*(BHW/4)/256 = 4096 blocks.
// Each thread: one float4 quad, 16 channels, 8-deep explicit load batches.
// TLP fix vs previous: 4096 blocks (vs 1024) and <=64 VGPR keeps 8 waves/SIMD.
// NT stores: partial must NOT evict the L3-resident input (input is exactly
// 256 MiB = Infinity Cache capacity; apply re-reads it from L3 — confirmed
// by round-3 counters: FETCH 265 MB for the whole fused computation).
// ---------------------------------------------------------------------------
__global__ __launch_bounds__(256)
void conv_partial_kernel(const float* __restrict__ in,
                         const float* __restrict__ wv,
                         float* __restrict__ partial) {
    int t = blockIdx.x * 256 + threadIdx.x;      // 0 .. 1048575
    int chunk = t >> 15;                         // 0..31 (block-uniform)
    int quad  = t & 32767;                       // spatial quad over B*HW/4
    int b = quad >> 12;
    int q = quad & (HWQ - 1);

    const float4* inp = (const float4*)in
        + (size_t)b * (C * HWQ)
        + (size_t)chunk * CPC * HWQ
        + q;
    const float* wc = wv + chunk * CPC;

    float4 acc = make_float4(0.f, 0.f, 0.f, 0.f);
    float4 v[8];
#pragma unroll
    for (int c0 = 0; c0 < CPC; c0 += 8) {
#pragma unroll
        for (int u = 0; u < 8; ++u)
            v[u] = inp[(size_t)(c0 + u) * HWQ];
#pragma unroll
        for (int u = 0; u < 8; ++u) {
            float wcc = wc[c0 + u];
            acc.x += v[u].x * wcc;
            acc.y += v[u].y * wcc;
            acc.z += v[u].z * wcc;
            acc.w += v[u].w * wcc;
        }
    }
    nfloat4 r;
    r.x = acc.x; r.y = acc.y; r.z = acc.z; r.w = acc.w;
    __builtin_nontemporal_store(
        r, (nfloat4*)((float4*)partial + (size_t)chunk * 32768 + quad));
}

// ---------------------------------------------------------------------------
// Kernel 2: reduce 32 partials -> x_proj, NT loads (keep input L3-resident).
// grid = 128 blocks; 8-deep load batches for ILP.
// ---------------------------------------------------------------------------
__global__ __launch_bounds__(256)
void reduce_partial_kernel(const float* __restrict__ partial,
                           float4* __restrict__ xproj) {
    int t = blockIdx.x * 256 + threadIdx.x;      // 0 .. 32767
    const nfloat4* pp = (const nfloat4*)partial;
    float4 s = make_float4(0.f, 0.f, 0.f, 0.f);
#pragma unroll
    for (int c0 = 0; c0 < NCHUNK; c0 += 8) {
        nfloat4 p[8];
#pragma unroll
        for (int u = 0; u < 8; ++u)
            p[u] = __builtin_nontemporal_load(
                pp + (size_t)(c0 + u) * 32768 + t);
#pragma unroll
        for (int u = 0; u < 8; ++u) {
            s.x += p[u].x;
            s.y += p[u].y;
            s.z += p[u].z;
            s.w += p[u].w;
        }
    }
    xproj[t] = s;
}

// ---------------------------------------------------------------------------
// Kernel 3: per-(b,mask) softmax stats over its 64x64 wrapped window.
// 128 blocks x 256 threads; coef[b*16+k] = exp(-max)/Z.  (unchanged, passed)
// ---------------------------------------------------------------------------
__global__ __launch_bounds__(256)
void stats_kernel(const float* __restrict__ xproj,
                  float* __restrict__ coef) {
    int bk = blockIdx.x;             // 0..127
    int b = bk >> 4, k = bk & 15;
    int i = k >> 2, j = k & 3;
    int h0 = (16 * i + ((j >> 1) ? 64 : 0)) & (H - 1);
    int w0 = (16 * i + ((j & 1) ? 64 : 0)) & (W - 1);
    const float* x = xproj + b * HW;

    int tid = threadIdx.x;
    float v[16];
    float m = -1e30f;
#pragma unroll
    for (int it = 0; it < 16; ++it) {
        int p = tid + 256 * it;          // 0..4095 window pixel
        int r = p >> 6, c = p & 63;
        int h = (h0 + r) & (H - 1);
        int w = (w0 + c) & (W - 1);
        v[it] = x[h * W + w];
        m = fmaxf(m, v[it]);
    }
    for (int off = 32; off > 0; off >>= 1)
        m = fmaxf(m, __shfl_down(m, off, 64));
    __shared__ float sm[4];
    __shared__ float ss[4];
    int lane = tid & 63, wv = tid >> 6;
    if (lane == 0) sm[wv] = m;
    __syncthreads();
    m = fmaxf(fmaxf(sm[0], sm[1]), fmaxf(sm[2], sm[3]));

    float s = 0.f;
#pragma unroll
    for (int it = 0; it < 16; ++it)
        s += expf(v[it] - m);
    for (int off = 32; off > 0; off >>= 1)
        s += __shfl_down(s, off, 64);
    if (lane == 0) ss[wv] = s;
    __syncthreads();
    if (tid == 0) {
        float Z = ss[0] + ss[1] + ss[2] + ss[3];
        coef[bk] = expf(-m) / Z;
    }
}

// ---------------------------------------------------------------------------
// Kernel 4: scale[b,hw] = 1 + exp(x) * sum_{i=0..3} coef[b, 4i+idx(i,h,w)]
// (unchanged, passed)
// ---------------------------------------------------------------------------
__global__ __launch_bounds__(256)
void scale_kernel(const float* __restrict__ xproj,
                  const float* __restrict__ coef,
                  float* __restrict__ scale) {
    int t = blockIdx.x * 256 + threadIdx.x;      // 0..BHW-1
    int b = t >> 14;
    int hw = t & (HW - 1);
    int h = hw >> 7, w = hw & (W - 1);
    const float* cf = coef + b * 16;
    float acc = 0.f;
#pragma unroll
    for (int i = 0; i < 4; ++i) {
        int hr = (h - 16 * i) & (H - 1);
        int wr = (w - 16 * i) & (W - 1);
        int idx = 4 * i + ((hr < 64) ? 0 : 2) + ((wr < 64) ? 0 : 1);
        acc += cf[idx];
    }
    scale[t] = 1.0f + expf(xproj[t]) * acc;
}

// ---------------------------------------------------------------------------
// Kernel 5: out = in * scale, float4, full TLP (65536 blocks).
// Reverse block order (read conv's most-recent lines first under LRU) and
// NT output stores (output must not evict the L3-resident input).
// (unchanged, passed)
// ---------------------------------------------------------------------------
__global__ __launch_bounds__(256)
void apply_kernel(const float4* __restrict__ in,
                  const float4* __restrict__ scale,
                  float4* __restrict__ out) {
    size_t base = (size_t)(gridDim.x - 1 - blockIdx.x) * 256;
    size_t t = base + threadIdx.x;           // 0..16777215 quads (reversed by block)
    float4 v = in[t];
    int b = (int)(t >> 21);                  // quads per batch = C*HW/4 = 2^21
    int q = (int)(t & (HWQ - 1));            // spatial quad
    float4 s = scale[((size_t)b << 12) + q];
    nfloat4 r;
    r.x = v.x * s.x;
    r.y = v.y * s.y;
    r.z = v.z * s.z;
    r.w = v.w * s.w;
    __builtin_nontemporal_store(r, (nfloat4*)&out[t]);
}

extern "C" void kernel_launch(void* const* d_in, const int* in_sizes, int n_in,
                              void* d_out, int out_size, void* d_ws, size_t ws_size,
                              hipStream_t stream) {
    const float* input  = (const float*)d_in[0];   // [8,512,128,128]
    const float* w_conv = (const float*)d_in[1];   // [512]
    float* out = (float*)d_out;                    // [8,512,128,128]

    // workspace (floats): partial[32*131072] | xproj[131072] | coef[128] | scale[131072]
    float* ws      = (float*)d_ws;
    float* partial = ws;                               // 4,194,304 floats (16 MB)
    float* xproj   = ws + (size_t)NCHUNK * BHW;        // +131072
    float* coef    = xproj + BHW;                      // +128
    float* scale   = coef + 128;                       // +131072 (16B-aligned)

    conv_partial_kernel<<<NCHUNK * (BHW / 4) / 256, 256, 0, stream>>>(
        input, w_conv, partial);
    reduce_partial_kernel<<<(BHW / 4) / 256, 256, 0, stream>>>(
        partial, (float4*)xproj);
    stats_kernel<<<B * 16, 256, 0, stream>>>(xproj, coef);
    scale_kernel<<<BHW / 256, 256, 0, stream>>>(xproj, coef, scale);
    apply_kernel<<<(B * C * HW / 4) / 256, 256, 0, stream>>>(
        (const float4*)input, (const float4*)scale, (float4*)out);
}